// Round 2
// baseline (122.118 us; speedup 1.0000x reference)
//
#include <hip/hip_runtime.h>

// Adaptive Wing loss, reduction='sum', fp32 in/out.
// THETA=0.5, ALPHA=2.1, OMEGA=14.0, EPS=1.0
//   p   = 2.1 - target                      in (1.1, 2.1]
//   t   = (0.5)^p = 2^(-p)
//   A   = 14 * p * 2^(-(p-1)) / (1+t) = 28 * p * t / (1+t)
//   C   = 0.5*A - 14*ln(1+t)
//   diff = |target - input|
//   loss = diff < 0.5 ? 14*ln(1 + diff^p) : A*diff - C
// Memory-bound: 537 MB read at ~6.3 TB/s -> ~85 us floor.

#define LN2_X14 9.704060527839234f  // 14 * ln(2)

__device__ __forceinline__ float awl_elem(float x, float tg) {
    float p = 2.1f - tg;
    float t = exp2f(-p);                                 // (theta/eps)^p, ratio=0.5
    float A = 28.0f * p * t / (1.0f + t);
    float C = fmaf(0.5f, A, -LN2_X14 * log2f(1.0f + t)); // 0.5A - 14*ln(1+t)
    float diff = fabsf(tg - x);
    float lin = fmaf(A, diff, -C);
    // diff^p = 2^(p * log2(diff)); diff==0 -> -inf exponent -> 2^-inf = 0 -> log2(1)=0. OK.
    float q = exp2f(p * log2f(diff));
    float nl = LN2_X14 * log2f(1.0f + q);                // 14*ln(1+diff^p)
    return diff < 0.5f ? nl : lin;
}

__global__ __launch_bounds__(256) void awl_partial(
    const float4* __restrict__ x, const float4* __restrict__ tg,
    float* __restrict__ part, int n4)
{
    int tid = blockIdx.x * blockDim.x + threadIdx.x;
    int stride = gridDim.x * blockDim.x;
    float acc = 0.0f;
    for (int i = tid; i < n4; i += stride) {
        float4 a = x[i];
        float4 b = tg[i];
        acc += awl_elem(a.x, b.x);
        acc += awl_elem(a.y, b.y);
        acc += awl_elem(a.z, b.z);
        acc += awl_elem(a.w, b.w);
    }
    // wave-64 reduce
    #pragma unroll
    for (int off = 32; off > 0; off >>= 1)
        acc += __shfl_down(acc, off, 64);
    __shared__ float ws[4];
    int lane = threadIdx.x & 63;
    int wid  = threadIdx.x >> 6;
    if (lane == 0) ws[wid] = acc;
    __syncthreads();
    if (threadIdx.x == 0)
        part[blockIdx.x] = (ws[0] + ws[1]) + (ws[2] + ws[3]);
}

__global__ __launch_bounds__(256) void awl_final(
    const float* __restrict__ part, int n, float* __restrict__ out)
{
    float acc = 0.0f;
    for (int i = threadIdx.x; i < n; i += 256) acc += part[i];
    #pragma unroll
    for (int off = 32; off > 0; off >>= 1)
        acc += __shfl_down(acc, off, 64);
    __shared__ float ws[4];
    int lane = threadIdx.x & 63;
    int wid  = threadIdx.x >> 6;
    if (lane == 0) ws[wid] = acc;
    __syncthreads();
    if (threadIdx.x == 0)
        out[0] = (ws[0] + ws[1]) + (ws[2] + ws[3]);
}

extern "C" void kernel_launch(void* const* d_in, const int* in_sizes, int n_in,
                              void* d_out, int out_size, void* d_ws, size_t ws_size,
                              hipStream_t stream) {
    const float* x  = (const float*)d_in[0];
    const float* tg = (const float*)d_in[1];
    float* out  = (float*)d_out;
    float* part = (float*)d_ws;

    long long n = (long long)in_sizes[0];   // 67,108,864 (divisible by 4)
    int n4 = (int)(n / 4);

    int nblk = 2048;                         // 8 blocks/CU, grid-stride covers rest
    int cap = (int)(ws_size / sizeof(float));
    if (cap > 0 && nblk > cap) nblk = cap;
    if (nblk < 1) nblk = 1;

    awl_partial<<<nblk, 256, 0, stream>>>((const float4*)x, (const float4*)tg, part, n4);
    awl_final<<<1, 256, 0, stream>>>(part, nblk, out);
}

// Round 3
// 100.969 us; speedup vs baseline: 1.2095x; 1.2095x over previous
//
#include <hip/hip_runtime.h>

// Adaptive Wing loss, reduction='sum', fp32 in/out.
// THETA=0.5, ALPHA=2.1, OMEGA=14.0, EPS=1.0
//   p   = 2.1 - target                      in (1.1, 2.1]
//   t   = (0.5)^p = 2^(-p)
//   A   = 28 * p * t / (1+t)
//   C   = 0.5*A - 14*ln(1+t)
//   diff = |target - input|
//   loss = diff < 0.5 ? 14*ln(1 + diff^p) : A*diff - C
//
// R2: libm exp2f/log2f were OCML precise expansions -> VALU-issue-bound
// (VALUBusy 62%, HBM 20%). Use native v_exp_f32/v_log_f32/v_rcp_f32 via
// __builtin_amdgcn_* (single instruction each, no glibc macro collision).

#define LN2_X14 9.704060527839234f  // 14 * ln(2)

__device__ __forceinline__ float awl_elem(float x, float tg) {
    float p = 2.1f - tg;
    float t = __builtin_amdgcn_exp2f(-p);                 // 2^(-p)
    float A = 28.0f * p * t * __builtin_amdgcn_rcpf(1.0f + t);
    // lin = A*diff - C = A*(diff - 0.5) + 14*ln(1+t)
    float l1pt = LN2_X14 * __builtin_amdgcn_logf(1.0f + t);
    float diff = fabsf(tg - x);
    float lin = fmaf(A, diff - 0.5f, l1pt);
    // diff^p = 2^(p*log2(diff)); diff==0 -> -inf -> exp2 = 0 -> log(1)=0. OK.
    float q = __builtin_amdgcn_exp2f(p * __builtin_amdgcn_logf(diff));
    float nl = LN2_X14 * __builtin_amdgcn_logf(1.0f + q);
    return diff < 0.5f ? nl : lin;
}

__global__ __launch_bounds__(256) void awl_partial(
    const float4* __restrict__ x, const float4* __restrict__ tg,
    float* __restrict__ part, int n4)
{
    int tid = blockIdx.x * blockDim.x + threadIdx.x;
    int stride = gridDim.x * blockDim.x;
    float acc = 0.0f;
    for (int i = tid; i < n4; i += stride) {
        float4 a = x[i];
        float4 b = tg[i];
        acc += awl_elem(a.x, b.x);
        acc += awl_elem(a.y, b.y);
        acc += awl_elem(a.z, b.z);
        acc += awl_elem(a.w, b.w);
    }
    // wave-64 reduce
    #pragma unroll
    for (int off = 32; off > 0; off >>= 1)
        acc += __shfl_down(acc, off, 64);
    __shared__ float ws[4];
    int lane = threadIdx.x & 63;
    int wid  = threadIdx.x >> 6;
    if (lane == 0) ws[wid] = acc;
    __syncthreads();
    if (threadIdx.x == 0)
        part[blockIdx.x] = (ws[0] + ws[1]) + (ws[2] + ws[3]);
}

__global__ __launch_bounds__(256) void awl_final(
    const float* __restrict__ part, int n, float* __restrict__ out)
{
    float acc = 0.0f;
    for (int i = threadIdx.x; i < n; i += 256) acc += part[i];
    #pragma unroll
    for (int off = 32; off > 0; off >>= 1)
        acc += __shfl_down(acc, off, 64);
    __shared__ float ws[4];
    int lane = threadIdx.x & 63;
    int wid  = threadIdx.x >> 6;
    if (lane == 0) ws[wid] = acc;
    __syncthreads();
    if (threadIdx.x == 0)
        out[0] = (ws[0] + ws[1]) + (ws[2] + ws[3]);
}

extern "C" void kernel_launch(void* const* d_in, const int* in_sizes, int n_in,
                              void* d_out, int out_size, void* d_ws, size_t ws_size,
                              hipStream_t stream) {
    const float* x  = (const float*)d_in[0];
    const float* tg = (const float*)d_in[1];
    float* out  = (float*)d_out;
    float* part = (float*)d_ws;

    long long n = (long long)in_sizes[0];   // 67,108,864 (divisible by 4)
    int n4 = (int)(n / 4);

    int nblk = 2048;                         // 8 blocks/CU, 32 waves/CU at 28 VGPR
    int cap = (int)(ws_size / sizeof(float));
    if (cap > 0 && nblk > cap) nblk = cap;
    if (nblk < 1) nblk = 1;

    awl_partial<<<nblk, 256, 0, stream>>>((const float4*)x, (const float4*)tg, part, n4);
    awl_final<<<1, 256, 0, stream>>>(part, nblk, out);
}